// Round 8
// baseline (186.944 us; speedup 1.0000x reference)
//
#include <hip/hip_runtime.h>
#include <hip/hip_bf16.h>

// ---------------- types ----------------
typedef __bf16 bf16;
typedef __attribute__((ext_vector_type(2))) __bf16 bf16x2;
typedef __attribute__((ext_vector_type(4))) __bf16 bf16x4;
typedef __attribute__((ext_vector_type(8))) __bf16 bf16x8;
typedef __attribute__((ext_vector_type(4))) float f32x4;
typedef __attribute__((ext_vector_type(16))) float f32x16;
typedef unsigned int u32;
typedef __attribute__((ext_vector_type(4))) u32 u32x4;
typedef const __attribute__((address_space(1))) u32* gptr_t;
typedef __attribute__((address_space(3))) u32* lptr_t;

#define N_EMB 1024
#define N_HEAD 16
#define HEAD_DIM 64
#define T_SEQ 2048
#define BATCH 2
#define M_TOT (BATCH * T_SEQ)   // 4096
#define N_QKV (3 * N_EMB)       // 3072
#define KDIM 1024
// scale * log2(e), folded into Q at the QKV epilogue
#define CS_LOG2E 0.1803368801111129f

// round-to-nearest-even f32 -> bf16
__device__ inline unsigned short f2bu(float f) {
    unsigned u = __builtin_bit_cast(unsigned, f);
    return (unsigned short)((u + 0x7fffu + ((u >> 16) & 1u)) >> 16);
}
__device__ inline bf16 f2b(float f) {
    unsigned short s = f2bu(f);
    return __builtin_bit_cast(bf16, s);
}
__device__ inline u32 pkbf(float lo, float hi) {
    bf16x2 t; t[0] = (bf16)lo; t[1] = (bf16)hi;
    return __builtin_bit_cast(u32, t);
}
// cross-half (lane ^ 32) reduce via shfl (proven R4-R6)
__device__ __forceinline__ float xhalf_max(float x) {
    return fmaxf(x, __shfl_xor(x, 32, 64));
}
__device__ __forceinline__ float xhalf_sum(float x) {
    return x + __shfl_xor(x, 32, 64);
}

// ---------------- cast x (f32 -> bf16) ----------------
__global__ __launch_bounds__(256) void k_cast(const float* __restrict__ x,
                                              bf16* __restrict__ xb, int n4) {
    int i = blockIdx.x * 256 + threadIdx.x;
    if (i < n4) {
        float4 v = reinterpret_cast<const float4*>(x)[i];
        ushort4 u;
        u.x = f2bu(v.x); u.y = f2bu(v.y); u.z = f2bu(v.z); u.w = f2bu(v.w);
        reinterpret_cast<ushort4*>(xb)[i] = u;
    }
}

// ---------------- transpose + cast: W [K][N] f32 -> Wt [N][K] bf16 ----------------
__global__ __launch_bounds__(256) void k_transpose(const float* __restrict__ W,
                                                   bf16* __restrict__ Wt,
                                                   int K, int N) {
    __shared__ float tile[32][33];
    int k0 = blockIdx.x * 32;
    int n0 = blockIdx.y * 32;
    int tx = threadIdx.x & 31;
    int ty = threadIdx.x >> 5;
    for (int j = 0; j < 32; j += 8)
        tile[ty + j][tx] = W[(k0 + ty + j) * N + n0 + tx];
    __syncthreads();
    for (int j = 0; j < 32; j += 8)
        Wt[(n0 + ty + j) * (long)K + k0 + tx] = f2b(tile[tx][ty + j]);
}

// ---------------- V transpose: [B,H,T,64] -> [B,H,64,T] via LDS tile ----------------
__global__ __launch_bounds__(256) void k_vtrans(const bf16* __restrict__ v,
                                                bf16* __restrict__ vt) {
    __shared__ bf16 tile[64 * 76];
    const int bh = blockIdx.y;
    const int t0 = blockIdx.x * 64;
    const bf16* src = v + (size_t)bh * T_SEQ * HEAD_DIM;
    bf16* dst = vt + (size_t)bh * HEAD_DIM * T_SEQ;
    const int tid = threadIdx.x;
    #pragma unroll
    for (int it = 0; it < 2; ++it) {
        const int row = (tid >> 3) + it * 32;
        const int col = (tid & 7) * 8;
        bf16x8 val = *reinterpret_cast<const bf16x8*>(src + (size_t)(t0 + row) * HEAD_DIM + col);
        bf16x4 lo;  lo[0] = val[0]; lo[1] = val[1]; lo[2] = val[2]; lo[3] = val[3];
        bf16x4 hiv; hiv[0] = val[4]; hiv[1] = val[5]; hiv[2] = val[6]; hiv[3] = val[7];
        *reinterpret_cast<bf16x4*>(&tile[row * 76 + col]) = lo;
        *reinterpret_cast<bf16x4*>(&tile[row * 76 + col + 4]) = hiv;
    }
    __syncthreads();
    #pragma unroll
    for (int it = 0; it < 2; ++it) {
        const int d  = (tid >> 3) + it * 32;
        const int tt = (tid & 7) * 8;
        bf16x8 val;
        #pragma unroll
        for (int q = 0; q < 8; ++q)
            val[q] = tile[(tt + q) * 76 + d];
        *reinterpret_cast<bf16x8*>(dst + (size_t)d * T_SEQ + t0 + tt) = val;
    }
}

// =====================================================================
// 128x128 GEMM main loop (m97 structure) — used by QKV
// =====================================================================
#define GEMM_MAINLOOP(A_, Bt_, m0_, n0_)                                          \
    __shared__ __align__(16) bf16 As[128 * 32];                                   \
    __shared__ __align__(16) bf16 Bs[128 * 32];                                   \
    const int lane = threadIdx.x & 63;                                            \
    const int w    = threadIdx.x >> 6;                                            \
    const int wr   = w >> 1;                                                      \
    const int wc   = w & 1;                                                       \
    const int r    = lane & 15;                                                   \
    const int ko   = (lane >> 4) * 8;                                             \
    const int srow = w * 32 + (lane >> 2);                                        \
    const int sk   = (lane & 3) * 8;                                              \
    const bf16* a_g0 = A_ + (size_t)(m0_ + srow) * KDIM + sk;                     \
    const bf16* a_g1 = a_g0 + 16 * KDIM;                                          \
    const bf16* b_g0 = Bt_ + (size_t)(n0_ + srow) * KDIM + sk;                    \
    const bf16* b_g1 = b_g0 + 16 * KDIM;                                          \
    bf16* a_l0 = As + (w * 2) * 512;                                              \
    bf16* a_l1 = As + (w * 2 + 1) * 512;                                          \
    bf16* b_l0 = Bs + (w * 2) * 512;                                              \
    bf16* b_l1 = Bs + (w * 2 + 1) * 512;                                          \
    f32x4 acc[4][4];                                                              \
    for (int i = 0; i < 4; ++i)                                                   \
        for (int j = 0; j < 4; ++j) acc[i][j] = (f32x4){0.f, 0.f, 0.f, 0.f};      \
    for (int k0 = 0; k0 < KDIM; k0 += 32) {                                       \
        __builtin_amdgcn_global_load_lds((gptr_t)(const void*)(a_g0 + k0),        \
                                         (lptr_t)(void*)a_l0, 16, 0, 0);          \
        __builtin_amdgcn_global_load_lds((gptr_t)(const void*)(a_g1 + k0),        \
                                         (lptr_t)(void*)a_l1, 16, 0, 0);          \
        __builtin_amdgcn_global_load_lds((gptr_t)(const void*)(b_g0 + k0),        \
                                         (lptr_t)(void*)b_l0, 16, 0, 0);          \
        __builtin_amdgcn_global_load_lds((gptr_t)(const void*)(b_g1 + k0),        \
                                         (lptr_t)(void*)b_l1, 16, 0, 0);          \
        __syncthreads();                                                          \
        bf16x8 af[4], bfr[4];                                                     \
        for (int m = 0; m < 4; ++m)                                               \
            af[m] = *reinterpret_cast<const bf16x8*>(As + (wr * 64 + m * 16 + r) * 32 + ko); \
        for (int n = 0; n < 4; ++n)                                               \
            bfr[n] = *reinterpret_cast<const bf16x8*>(Bs + (wc * 64 + n * 16 + r) * 32 + ko); \
        for (int m = 0; m < 4; ++m)                                               \
            for (int n = 0; n < 4; ++n)                                           \
                acc[m][n] = __builtin_amdgcn_mfma_f32_16x16x32_bf16(af[m], bfr[n], acc[m][n], 0, 0, 0); \
        __syncthreads();                                                          \
    }

// =====================================================================
// 64x128 GEMM main loop — used by proj
// =====================================================================
#define GEMM_MAINLOOP_64(A_, Bt_, m0_, n0_)                                       \
    __shared__ __align__(16) bf16 As[64 * 32];                                    \
    __shared__ __align__(16) bf16 Bs[128 * 32];                                   \
    const int lane = threadIdx.x & 63;                                            \
    const int w    = threadIdx.x >> 6;                                            \
    const int wr   = w >> 1;                                                      \
    const int wc   = w & 1;                                                       \
    const int r    = lane & 15;                                                   \
    const int ko   = (lane >> 4) * 8;                                             \
    const int srow = w * 16 + (lane >> 2);                                        \
    const int sk   = (lane & 3) * 8;                                              \
    const bf16* a_g0 = A_ + (size_t)(m0_ + srow) * KDIM + sk;                     \
    const bf16* b_g0 = Bt_ + (size_t)(n0_ + srow) * KDIM + sk;                    \
    const bf16* b_g1 = b_g0 + 64 * KDIM;                                          \
    bf16* a_l0 = As + w * 512;                                                    \
    bf16* b_l0 = Bs + w * 512;                                                    \
    bf16* b_l1 = Bs + 64 * 32 + w * 512;                                          \
    f32x4 acc[2][4];                                                              \
    for (int i = 0; i < 2; ++i)                                                   \
        for (int j = 0; j < 4; ++j) acc[i][j] = (f32x4){0.f, 0.f, 0.f, 0.f};      \
    for (int k0 = 0; k0 < KDIM; k0 += 32) {                                       \
        __builtin_amdgcn_global_load_lds((gptr_t)(const void*)(a_g0 + k0),        \
                                         (lptr_t)(void*)a_l0, 16, 0, 0);          \
        __builtin_amdgcn_global_load_lds((gptr_t)(const void*)(b_g0 + k0),        \
                                         (lptr_t)(void*)b_l0, 16, 0, 0);          \
        __builtin_amdgcn_global_load_lds((gptr_t)(const void*)(b_g1 + k0),        \
                                         (lptr_t)(void*)b_l1, 16, 0, 0);          \
        __syncthreads();                                                          \
        bf16x8 af[2], bfr[4];                                                     \
        for (int m = 0; m < 2; ++m)                                               \
            af[m] = *reinterpret_cast<const bf16x8*>(As + (wr * 32 + m * 16 + r) * 32 + ko); \
        for (int n = 0; n < 4; ++n)                                               \
            bfr[n] = *reinterpret_cast<const bf16x8*>(Bs + (wc * 64 + n * 16 + r) * 32 + ko); \
        for (int m = 0; m < 2; ++m)                                               \
            for (int n = 0; n < 4; ++n)                                           \
                acc[m][n] = __builtin_amdgcn_mfma_f32_16x16x32_bf16(af[m], bfr[n], acc[m][n], 0, 0, 0); \
        __syncthreads();                                                          \
    }

// ---------------- QKV GEMM -> q/k/v [B,H,T,64] bf16 (q pre-scaled by CS_LOG2E) ----------------
__global__ __launch_bounds__(256) void k_gemm_qkv(const bf16* __restrict__ A,
                                                  const bf16* __restrict__ Bt,
                                                  const float* __restrict__ bias,
                                                  bf16* __restrict__ qb,
                                                  bf16* __restrict__ kb,
                                                  bf16* __restrict__ vb) {
    const int m0 = blockIdx.x * 128;
    const int n0 = blockIdx.y * 128;
    GEMM_MAINLOOP(A, Bt, m0, n0)
    const int col   = lane & 15;
    const int rbase = (lane >> 4) * 4;
    for (int nn = 0; nn < 4; ++nn) {
        int n = n0 + wc * 64 + nn * 16 + col;
        float bv = bias[n];
        int which = n >> 10;
        int c  = n & 1023;
        int h  = c >> 6;
        int dh = c & 63;
        bf16* dst = (which == 0) ? qb : ((which == 1) ? kb : vb);
        const float sc = (which == 0) ? CS_LOG2E : 1.0f;
        for (int mm = 0; mm < 4; ++mm) {
            for (int i = 0; i < 4; ++i) {
                int m = m0 + wr * 64 + mm * 16 + rbase + i;
                int b_ = m >> 11;
                int t  = m & 2047;
                dst[(((b_ * N_HEAD + h) * T_SEQ) + t) * HEAD_DIM + dh] =
                    f2b((acc[mm][nn][i] + bv) * sc);
            }
        }
    }
}

// ---------------- proj GEMM (64x128 tiles) ----------------
__global__ __launch_bounds__(256) void k_gemm_proj(const bf16* __restrict__ A,
                                                   const bf16* __restrict__ Bt,
                                                   const float* __restrict__ bias,
                                                   float* __restrict__ out) {
    const int m0 = blockIdx.x * 64;
    const int n0 = blockIdx.y * 128;
    GEMM_MAINLOOP_64(A, Bt, m0, n0)
    const int col   = lane & 15;
    const int rbase = (lane >> 4) * 4;
    for (int nn = 0; nn < 4; ++nn) {
        int n = n0 + wc * 64 + nn * 16 + col;
        float bv = bias[n];
        for (int mm = 0; mm < 2; ++mm) {
            for (int i = 0; i < 4; ++i) {
                int m = m0 + wr * 32 + mm * 16 + rbase + i;
                out[(size_t)m * N_EMB + n] = acc[mm][nn][i] + bv;
            }
        }
    }
}

// =====================================================================
// flash attention helpers (swapped-operand 32x32; Q pre-scaled so S is
// already in log2 units). Cross-lane via __shfl_xor (proven R4-R6).
// =====================================================================
__device__ __forceinline__ void pv_group(const float* p, int hi,
                                         const bf16x8 (&va)[2][2], f32x16 (&o)[2]) {
    u32 c[8], sw[8];
    #pragma unroll
    for (int i = 0; i < 8; ++i) c[i] = pkbf(p[2 * i], p[2 * i + 1]);
    #pragma unroll
    for (int i = 0; i < 8; ++i) sw[i] = __shfl_xor(c[i], 32, 64);
    u32x4 f0, f1;
    f0[0] = hi ? sw[2] : c[0];  f0[1] = hi ? sw[3] : c[1];
    f0[2] = hi ? c[2]  : sw[0]; f0[3] = hi ? c[3]  : sw[1];
    f1[0] = hi ? sw[6] : c[4];  f1[1] = hi ? sw[7] : c[5];
    f1[2] = hi ? c[6]  : sw[4]; f1[3] = hi ? c[7]  : sw[5];
    bf16x8 pb0 = __builtin_bit_cast(bf16x8, f0);
    bf16x8 pb1 = __builtin_bit_cast(bf16x8, f1);
    __builtin_amdgcn_s_setprio(1);
    #pragma unroll
    for (int dt = 0; dt < 2; ++dt) {
        o[dt] = __builtin_amdgcn_mfma_f32_32x32x16_bf16(va[dt][0], pb0, o[dt], 0, 0, 0);
        o[dt] = __builtin_amdgcn_mfma_f32_32x32x16_bf16(va[dt][1], pb1, o[dt], 0, 0, 0);
    }
    __builtin_amdgcn_s_setprio(0);
}

__device__ __forceinline__ float tree_max16(const f32x16& v) {
    float a0 = fmaxf(v[0], v[1]),   a1 = fmaxf(v[2], v[3]);
    float a2 = fmaxf(v[4], v[5]),   a3 = fmaxf(v[6], v[7]);
    float a4 = fmaxf(v[8], v[9]),   a5 = fmaxf(v[10], v[11]);
    float a6 = fmaxf(v[12], v[13]), a7 = fmaxf(v[14], v[15]);
    float b0 = fmaxf(a0, a1), b1 = fmaxf(a2, a3);
    float b2 = fmaxf(a4, a5), b3 = fmaxf(a6, a7);
    return fmaxf(fmaxf(b0, b1), fmaxf(b2, b3));
}

// 64-wide KV tile; DIAG_HI: second 32-group is the diagonal (mask kpos<=qr)
template<bool DIAG_HI>
__device__ __forceinline__ void attn_tile64(
    const bf16* __restrict__ K, const bf16* __restrict__ Vt, int kbase,
    int qr, int hi, const bf16x8 (&qf)[4],
    float& m_r, float& l_r, f32x16 (&o)[2]) {
    bf16x8 kf0[4], kf1[4];
    #pragma unroll
    for (int f = 0; f < 4; ++f) {
        kf0[f] = *reinterpret_cast<const bf16x8*>(
            K + (size_t)(kbase + qr) * HEAD_DIM + f * 16 + hi * 8);
        kf1[f] = *reinterpret_cast<const bf16x8*>(
            K + (size_t)(kbase + 32 + qr) * HEAD_DIM + f * 16 + hi * 8);
    }
    bf16x8 va0[2][2], va1[2][2];
    #pragma unroll
    for (int dt = 0; dt < 2; ++dt)
        #pragma unroll
        for (int ks = 0; ks < 2; ++ks) {
            va0[dt][ks] = *reinterpret_cast<const bf16x8*>(
                Vt + (size_t)(dt * 32 + qr) * T_SEQ + kbase + ks * 16 + hi * 8);
            va1[dt][ks] = *reinterpret_cast<const bf16x8*>(
                Vt + (size_t)(dt * 32 + qr) * T_SEQ + kbase + 32 + ks * 16 + hi * 8);
        }
    f32x16 st0, st1;
    #pragma unroll
    for (int r = 0; r < 16; ++r) { st0[r] = 0.f; st1[r] = 0.f; }
    __builtin_amdgcn_s_setprio(1);
    #pragma unroll
    for (int f = 0; f < 4; ++f)
        st0 = __builtin_amdgcn_mfma_f32_32x32x16_bf16(kf0[f], qf[f], st0, 0, 0, 0);
    #pragma unroll
    for (int f = 0; f < 4; ++f)
        st1 = __builtin_amdgcn_mfma_f32_32x32x16_bf16(kf1[f], qf[f], st1, 0, 0, 0);
    __builtin_amdgcn_s_setprio(0);
    if (DIAG_HI) {
        const int kp4 = 4 * hi;
        #pragma unroll
        for (int r = 0; r < 16; ++r) {
            const int kpos = (r & 3) + 8 * (r >> 2) + kp4;
            if (kpos > qr) st1[r] = -3.0e38f;
        }
    }
    float mt = fmaxf(tree_max16(st0), tree_max16(st1));
    mt = xhalf_max(mt);
    if (!__all(mt <= m_r + 8.f)) {       // defer-max (T13), log2 domain
        const float mn = fmaxf(m_r, mt);
        const float alpha = exp2f(m_r - mn);
        m_r = mn;
        l_r *= alpha;
        #pragma unroll
        for (int r = 0; r < 16; ++r) { o[0][r] *= alpha; o[1][r] *= alpha; }
    }
    float p0[16], p1[16];
    #pragma unroll
    for (int r = 0; r < 16; ++r) { p0[r] = exp2f(st0[r] - m_r); }
    #pragma unroll
    for (int r = 0; r < 16; ++r) { p1[r] = exp2f(st1[r] - m_r); }
    float s0 = 0.f, s1 = 0.f;
    #pragma unroll
    for (int r = 0; r < 8; ++r) { s0 += p0[r] + p0[r + 8]; s1 += p1[r] + p1[r + 8]; }
    l_r += xhalf_sum(s0 + s1);
    pv_group(p0, hi, va0, o);
    pv_group(p1, hi, va1, o);
}

// 32-wide KV tile; DIAG_MASK: apply causal mask
template<bool DIAG_MASK>
__device__ __forceinline__ void attn_tile32(
    const bf16* __restrict__ K, const bf16* __restrict__ Vt, int kbase,
    int qr, int hi, const bf16x8 (&qf)[4],
    float& m_r, float& l_r, f32x16 (&o)[2]) {
    bf16x8 kf[4];
    #pragma unroll
    for (int f = 0; f < 4; ++f)
        kf[f] = *reinterpret_cast<const bf16x8*>(
            K + (size_t)(kbase + qr) * HEAD_DIM + f * 16 + hi * 8);
    bf16x8 va[2][2];
    #pragma unroll
    for (int dt = 0; dt < 2; ++dt)
        #pragma unroll
        for (int ks = 0; ks < 2; ++ks)
            va[dt][ks] = *reinterpret_cast<const bf16x8*>(
                Vt + (size_t)(dt * 32 + qr) * T_SEQ + kbase + ks * 16 + hi * 8);
    f32x16 st;
    #pragma unroll
    for (int r = 0; r < 16; ++r) st[r] = 0.f;
    __builtin_amdgcn_s_setprio(1);
    #pragma unroll
    for (int f = 0; f < 4; ++f)
        st = __builtin_amdgcn_mfma_f32_32x32x16_bf16(kf[f], qf[f], st, 0, 0, 0);
    __builtin_amdgcn_s_setprio(0);
    if (DIAG_MASK) {
        const int kp4 = 4 * hi;
        #pragma unroll
        for (int r = 0; r < 16; ++r) {
            const int kpos = (r & 3) + 8 * (r >> 2) + kp4;
            if (kpos > qr) st[r] = -3.0e38f;
        }
    }
    float mt = xhalf_max(tree_max16(st));
    if (!__all(mt <= m_r + 8.f)) {
        const float mn = fmaxf(m_r, mt);
        const float alpha = exp2f(m_r - mn);
        m_r = mn;
        l_r *= alpha;
        #pragma unroll
        for (int r = 0; r < 16; ++r) { o[0][r] *= alpha; o[1][r] *= alpha; }
    }
    float p[16];
    #pragma unroll
    for (int r = 0; r < 16; ++r) p[r] = exp2f(st[r] - m_r);
    float s = 0.f;
    #pragma unroll
    for (int r = 0; r < 8; ++r) s += p[r] + p[r + 8];
    l_r += xhalf_sum(s);
    pv_group(p, hi, va, o);
}

// =====================================================================
// flash attention: block = 2 waves sharing (bh, qblk); split-K halves,
// flash-combine via LDS. grid (bh=32, j=64): lin id % 8 = bh % 8 -> head
// pinned to XCD; qblk = 63-j -> heavy blocks dispatch first.
// 4096 waves total = 16 waves/CU = 4/SIMD.
// =====================================================================
__global__ __launch_bounds__(128, 4) void k_attn(const bf16* __restrict__ qb,
                                                 const bf16* __restrict__ kb,
                                                 const bf16* __restrict__ vtb,
                                                 bf16* __restrict__ yb) {
    const int lane = threadIdx.x & 63;
    const int wv   = threadIdx.x >> 6;   // 0 or 1
    const int bh   = blockIdx.x;         // 0..31  (XCD = bh % 8)
    const int qblk = 63 - blockIdx.y;
    const int q0   = qblk * 32;
    const int b    = bh >> 4;
    const int h    = bh & 15;

    const bf16* Q  = qb  + (size_t)bh * T_SEQ * HEAD_DIM;
    const bf16* K  = kb  + (size_t)bh * T_SEQ * HEAD_DIM;
    const bf16* Vt = vtb + (size_t)bh * HEAD_DIM * T_SEQ;

    const int qr = lane & 31;
    const int hi = lane >> 5;

    bf16x8 qf[4];
    #pragma unroll
    for (int f = 0; f < 4; ++f)
        qf[f] = *reinterpret_cast<const bf16x8*>(
            Q + (size_t)(q0 + qr) * HEAD_DIM + f * 16 + hi * 8);

    f32x16 o[2];
    #pragma unroll
    for (int r = 0; r < 16; ++r) { o[0][r] = 0.f; o[1][r] = 0.f; }
    float m_r = -3.0e38f, l_r = 0.f;

    // split-K: wave0 = tiles [0, h0), wave1 = [h0, n) (incl. diagonal)
    const int n  = qblk + 1;
    const int h0 = n - (n >> 1);
    const int lo  = wv ? h0 : 0;
    const int end = wv ? n  : h0;
    const bool has_diag = (end == n) && (end > lo);
    const int nd_end = has_diag ? end - 1 : end;

    int t = lo;
    while (t + 2 <= nd_end) {
        attn_tile64<false>(K, Vt, t * 32, qr, hi, qf, m_r, l_r, o);
        t += 2;
    }
    if (has_diag) {
        if (nd_end - t == 1)
            attn_tile64<true>(K, Vt, t * 32, qr, hi, qf, m_r, l_r, o);
        else
            attn_tile32<true>(K, Vt, qblk * 32, qr, hi, qf, m_r, l_r, o);
    } else if (t < end) {
        attn_tile32<false>(K, Vt, t * 32, qr, hi, qf, m_r, l_r, o);
    }

    // ---- flash-combine across the 2 waves via LDS ----
    __shared__ float ls_o[64][33];   // +1 pad: conflict-free column reads
    __shared__ float ls_m[64];
    __shared__ float ls_l[64];
    if (wv == 1) {
        #pragma unroll
        for (int i = 0; i < 16; ++i) {
            ls_o[lane][i]      = o[0][i];
            ls_o[lane][16 + i] = o[1][i];
        }
        ls_m[lane] = m_r;
        ls_l[lane] = l_r;
    }
    __syncthreads();
    if (wv == 1) return;
    const float m1 = ls_m[lane];
    const float l1 = ls_l[lane];
    const float mN = fmaxf(m_r, m1);
    const float a0 = exp2f(m_r - mN);
    const float a1 = (m1 > -1.0e37f) ? exp2f(m1 - mN) : 0.f;  // guard empty wave1
    l_r = l_r * a0 + l1 * a1;
    #pragma unroll
    for (int i = 0; i < 16; ++i) {
        o[0][i] = o[0][i] * a0 + ls_o[lane][i]      * a1;
        o[1][i] = o[1][i] * a0 + ls_o[lane][16 + i] * a1;
    }

    // epilogue: O^T[d][q] / l  -> y[b][t][h*64+d]
    const float inv = 1.f / fmaxf(l_r, 1e-30f);   // defensive: no 0/0 -> NaN
    const int tq = q0 + qr;
    bf16* yrow = yb + ((size_t)(b * T_SEQ + tq)) * N_EMB + h * HEAD_DIM;
    #pragma unroll
    for (int dt = 0; dt < 2; ++dt) {
        #pragma unroll
        for (int rr = 0; rr < 4; ++rr) {
            const int d0 = dt * 32 + 8 * rr + 4 * hi;
            ushort4 u;
            u.x = f2bu(o[dt][4 * rr + 0] * inv);
            u.y = f2bu(o[dt][4 * rr + 1] * inv);
            u.z = f2bu(o[dt][4 * rr + 2] * inv);
            u.w = f2bu(o[dt][4 * rr + 3] * inv);
            *reinterpret_cast<ushort4*>(yrow + d0) = u;
        }
    }
}

extern "C" void kernel_launch(void* const* d_in, const int* in_sizes, int n_in,
                              void* d_out, int out_size, void* d_ws, size_t ws_size,
                              hipStream_t stream) {
    const float* x      = (const float*)d_in[0];
    const float* W_attn = (const float*)d_in[1];
    const float* b_attn = (const float*)d_in[2];
    const float* W_proj = (const float*)d_in[3];
    const float* b_proj = (const float*)d_in[4];
    float* out = (float*)d_out;

    const size_t sz_x   = (size_t)M_TOT * N_EMB;
    const size_t sz_wat = (size_t)N_QKV * N_EMB;
    const size_t sz_wpt = (size_t)N_EMB * N_EMB;
    const size_t sz_hd  = (size_t)BATCH * N_HEAD * T_SEQ * HEAD_DIM;
    const size_t need = (sz_x + sz_wat + sz_wpt + 3 * sz_hd + sz_x) * sizeof(bf16);
    if (ws_size < need) return;

    bf16* xb  = (bf16*)d_ws;       // dead after QKV GEMM -> reused for V^T
    bf16* wat = xb + sz_x;
    bf16* wpt = wat + sz_wat;
    bf16* qb  = wpt + sz_wpt;
    bf16* kbf = qb + sz_hd;
    bf16* vbf = kbf + sz_hd;
    bf16* yb  = vbf + sz_hd;
    bf16* vtb = xb;                // V^T [B,H,64,T]

    k_cast<<<dim3((sz_x / 4 + 255) / 256), 256, 0, stream>>>(x, xb, (int)(sz_x / 4));
    k_transpose<<<dim3(N_EMB / 32, N_QKV / 32), 256, 0, stream>>>(W_attn, wat, N_EMB, N_QKV);
    k_transpose<<<dim3(N_EMB / 32, N_EMB / 32), 256, 0, stream>>>(W_proj, wpt, N_EMB, N_EMB);
    k_gemm_qkv<<<dim3(M_TOT / 128, N_QKV / 128), 256, 0, stream>>>(xb, wat, b_attn, qb, kbf, vbf);
    k_vtrans<<<dim3(T_SEQ / 64, BATCH * N_HEAD), 256, 0, stream>>>(vbf, vtb);
    k_attn<<<dim3(BATCH * N_HEAD, 64), 128, 0, stream>>>(qb, kbf, vtb, yb);
    k_gemm_proj<<<dim3(M_TOT / 64, N_EMB / 128), 256, 0, stream>>>(yb, wpt, b_proj, out);
}

// Round 9
// 139.230 us; speedup vs baseline: 1.3427x; 1.3427x over previous
//
#include <hip/hip_runtime.h>
#include <hip/hip_bf16.h>

// ---------------- types ----------------
typedef __bf16 bf16;
typedef __attribute__((ext_vector_type(2))) __bf16 bf16x2;
typedef __attribute__((ext_vector_type(4))) __bf16 bf16x4;
typedef __attribute__((ext_vector_type(8))) __bf16 bf16x8;
typedef __attribute__((ext_vector_type(4))) float f32x4;
typedef __attribute__((ext_vector_type(16))) float f32x16;
typedef unsigned int u32;
typedef __attribute__((ext_vector_type(4))) u32 u32x4;
typedef const __attribute__((address_space(1))) u32* gptr_t;
typedef __attribute__((address_space(3))) u32* lptr_t;

#define N_EMB 1024
#define N_HEAD 16
#define HEAD_DIM 64
#define T_SEQ 2048
#define BATCH 2
#define M_TOT (BATCH * T_SEQ)   // 4096
#define N_QKV (3 * N_EMB)       // 3072
#define KDIM 1024
// scale * log2(e), folded into Q at the QKV epilogue
#define CS_LOG2E 0.1803368801111129f

// round-to-nearest-even f32 -> bf16
__device__ inline unsigned short f2bu(float f) {
    unsigned u = __builtin_bit_cast(unsigned, f);
    return (unsigned short)((u + 0x7fffu + ((u >> 16) & 1u)) >> 16);
}
__device__ inline bf16 f2b(float f) {
    unsigned short s = f2bu(f);
    return __builtin_bit_cast(bf16, s);
}
__device__ inline u32 pkbf(float lo, float hi) {
    bf16x2 t; t[0] = (bf16)lo; t[1] = (bf16)hi;
    return __builtin_bit_cast(u32, t);
}
// cross-half (lane ^ 32) reduce via shfl (proven R4-R6)
__device__ __forceinline__ float xhalf_max(float x) {
    return fmaxf(x, __shfl_xor(x, 32, 64));
}
__device__ __forceinline__ float xhalf_sum(float x) {
    return x + __shfl_xor(x, 32, 64);
}

// ---------------- cast x (f32 -> bf16) ----------------
__global__ __launch_bounds__(256) void k_cast(const float* __restrict__ x,
                                              bf16* __restrict__ xb, int n4) {
    int i = blockIdx.x * 256 + threadIdx.x;
    if (i < n4) {
        float4 v = reinterpret_cast<const float4*>(x)[i];
        ushort4 u;
        u.x = f2bu(v.x); u.y = f2bu(v.y); u.z = f2bu(v.z); u.w = f2bu(v.w);
        reinterpret_cast<ushort4*>(xb)[i] = u;
    }
}

// ---------------- transpose + cast: W [K][N] f32 -> Wt [N][K] bf16 ----------------
__global__ __launch_bounds__(256) void k_transpose(const float* __restrict__ W,
                                                   bf16* __restrict__ Wt,
                                                   int K, int N) {
    __shared__ float tile[32][33];
    int k0 = blockIdx.x * 32;
    int n0 = blockIdx.y * 32;
    int tx = threadIdx.x & 31;
    int ty = threadIdx.x >> 5;
    for (int j = 0; j < 32; j += 8)
        tile[ty + j][tx] = W[(k0 + ty + j) * N + n0 + tx];
    __syncthreads();
    for (int j = 0; j < 32; j += 8)
        Wt[(n0 + ty + j) * (long)K + k0 + tx] = f2b(tile[tx][ty + j]);
}

// ---------------- V transpose: [B,H,T,64] -> [B,H,64,T] via LDS tile ----------------
__global__ __launch_bounds__(256) void k_vtrans(const bf16* __restrict__ v,
                                                bf16* __restrict__ vt) {
    __shared__ bf16 tile[64 * 76];
    const int bh = blockIdx.y;
    const int t0 = blockIdx.x * 64;
    const bf16* src = v + (size_t)bh * T_SEQ * HEAD_DIM;
    bf16* dst = vt + (size_t)bh * HEAD_DIM * T_SEQ;
    const int tid = threadIdx.x;
    #pragma unroll
    for (int it = 0; it < 2; ++it) {
        const int row = (tid >> 3) + it * 32;
        const int col = (tid & 7) * 8;
        bf16x8 val = *reinterpret_cast<const bf16x8*>(src + (size_t)(t0 + row) * HEAD_DIM + col);
        bf16x4 lo;  lo[0] = val[0]; lo[1] = val[1]; lo[2] = val[2]; lo[3] = val[3];
        bf16x4 hiv; hiv[0] = val[4]; hiv[1] = val[5]; hiv[2] = val[6]; hiv[3] = val[7];
        *reinterpret_cast<bf16x4*>(&tile[row * 76 + col]) = lo;
        *reinterpret_cast<bf16x4*>(&tile[row * 76 + col + 4]) = hiv;
    }
    __syncthreads();
    #pragma unroll
    for (int it = 0; it < 2; ++it) {
        const int d  = (tid >> 3) + it * 32;
        const int tt = (tid & 7) * 8;
        bf16x8 val;
        #pragma unroll
        for (int q = 0; q < 8; ++q)
            val[q] = tile[(tt + q) * 76 + d];
        *reinterpret_cast<bf16x8*>(dst + (size_t)d * T_SEQ + t0 + tt) = val;
    }
}

// =====================================================================
// 128x128 GEMM main loop (m97 structure) — used by QKV
// =====================================================================
#define GEMM_MAINLOOP(A_, Bt_, m0_, n0_)                                          \
    __shared__ __align__(16) bf16 As[128 * 32];                                   \
    __shared__ __align__(16) bf16 Bs[128 * 32];                                   \
    const int lane = threadIdx.x & 63;                                            \
    const int w    = threadIdx.x >> 6;                                            \
    const int wr   = w >> 1;                                                      \
    const int wc   = w & 1;                                                       \
    const int r    = lane & 15;                                                   \
    const int ko   = (lane >> 4) * 8;                                             \
    const int srow = w * 32 + (lane >> 2);                                        \
    const int sk   = (lane & 3) * 8;                                              \
    const bf16* a_g0 = A_ + (size_t)(m0_ + srow) * KDIM + sk;                     \
    const bf16* a_g1 = a_g0 + 16 * KDIM;                                          \
    const bf16* b_g0 = Bt_ + (size_t)(n0_ + srow) * KDIM + sk;                    \
    const bf16* b_g1 = b_g0 + 16 * KDIM;                                          \
    bf16* a_l0 = As + (w * 2) * 512;                                              \
    bf16* a_l1 = As + (w * 2 + 1) * 512;                                          \
    bf16* b_l0 = Bs + (w * 2) * 512;                                              \
    bf16* b_l1 = Bs + (w * 2 + 1) * 512;                                          \
    f32x4 acc[4][4];                                                              \
    for (int i = 0; i < 4; ++i)                                                   \
        for (int j = 0; j < 4; ++j) acc[i][j] = (f32x4){0.f, 0.f, 0.f, 0.f};      \
    for (int k0 = 0; k0 < KDIM; k0 += 32) {                                       \
        __builtin_amdgcn_global_load_lds((gptr_t)(const void*)(a_g0 + k0),        \
                                         (lptr_t)(void*)a_l0, 16, 0, 0);          \
        __builtin_amdgcn_global_load_lds((gptr_t)(const void*)(a_g1 + k0),        \
                                         (lptr_t)(void*)a_l1, 16, 0, 0);          \
        __builtin_amdgcn_global_load_lds((gptr_t)(const void*)(b_g0 + k0),        \
                                         (lptr_t)(void*)b_l0, 16, 0, 0);          \
        __builtin_amdgcn_global_load_lds((gptr_t)(const void*)(b_g1 + k0),        \
                                         (lptr_t)(void*)b_l1, 16, 0, 0);          \
        __syncthreads();                                                          \
        bf16x8 af[4], bfr[4];                                                     \
        for (int m = 0; m < 4; ++m)                                               \
            af[m] = *reinterpret_cast<const bf16x8*>(As + (wr * 64 + m * 16 + r) * 32 + ko); \
        for (int n = 0; n < 4; ++n)                                               \
            bfr[n] = *reinterpret_cast<const bf16x8*>(Bs + (wc * 64 + n * 16 + r) * 32 + ko); \
        for (int m = 0; m < 4; ++m)                                               \
            for (int n = 0; n < 4; ++n)                                           \
                acc[m][n] = __builtin_amdgcn_mfma_f32_16x16x32_bf16(af[m], bfr[n], acc[m][n], 0, 0, 0); \
        __syncthreads();                                                          \
    }

// =====================================================================
// 64x128 GEMM main loop — used by proj
// =====================================================================
#define GEMM_MAINLOOP_64(A_, Bt_, m0_, n0_)                                       \
    __shared__ __align__(16) bf16 As[64 * 32];                                    \
    __shared__ __align__(16) bf16 Bs[128 * 32];                                   \
    const int lane = threadIdx.x & 63;                                            \
    const int w    = threadIdx.x >> 6;                                            \
    const int wr   = w >> 1;                                                      \
    const int wc   = w & 1;                                                       \
    const int r    = lane & 15;                                                   \
    const int ko   = (lane >> 4) * 8;                                             \
    const int srow = w * 16 + (lane >> 2);                                        \
    const int sk   = (lane & 3) * 8;                                              \
    const bf16* a_g0 = A_ + (size_t)(m0_ + srow) * KDIM + sk;                     \
    const bf16* b_g0 = Bt_ + (size_t)(n0_ + srow) * KDIM + sk;                    \
    const bf16* b_g1 = b_g0 + 64 * KDIM;                                          \
    bf16* a_l0 = As + w * 512;                                                    \
    bf16* b_l0 = Bs + w * 512;                                                    \
    bf16* b_l1 = Bs + 64 * 32 + w * 512;                                          \
    f32x4 acc[2][4];                                                              \
    for (int i = 0; i < 2; ++i)                                                   \
        for (int j = 0; j < 4; ++j) acc[i][j] = (f32x4){0.f, 0.f, 0.f, 0.f};      \
    for (int k0 = 0; k0 < KDIM; k0 += 32) {                                       \
        __builtin_amdgcn_global_load_lds((gptr_t)(const void*)(a_g0 + k0),        \
                                         (lptr_t)(void*)a_l0, 16, 0, 0);          \
        __builtin_amdgcn_global_load_lds((gptr_t)(const void*)(b_g0 + k0),        \
                                         (lptr_t)(void*)b_l0, 16, 0, 0);          \
        __builtin_amdgcn_global_load_lds((gptr_t)(const void*)(b_g1 + k0),        \
                                         (lptr_t)(void*)b_l1, 16, 0, 0);          \
        __syncthreads();                                                          \
        bf16x8 af[2], bfr[4];                                                     \
        for (int m = 0; m < 2; ++m)                                               \
            af[m] = *reinterpret_cast<const bf16x8*>(As + (wr * 32 + m * 16 + r) * 32 + ko); \
        for (int n = 0; n < 4; ++n)                                               \
            bfr[n] = *reinterpret_cast<const bf16x8*>(Bs + (wc * 64 + n * 16 + r) * 32 + ko); \
        for (int m = 0; m < 2; ++m)                                               \
            for (int n = 0; n < 4; ++n)                                           \
                acc[m][n] = __builtin_amdgcn_mfma_f32_16x16x32_bf16(af[m], bfr[n], acc[m][n], 0, 0, 0); \
        __syncthreads();                                                          \
    }

// ---------------- QKV GEMM -> q/k/v [B,H,T,64] bf16 (q pre-scaled by CS_LOG2E) ----------------
__global__ __launch_bounds__(256) void k_gemm_qkv(const bf16* __restrict__ A,
                                                  const bf16* __restrict__ Bt,
                                                  const float* __restrict__ bias,
                                                  bf16* __restrict__ qb,
                                                  bf16* __restrict__ kb,
                                                  bf16* __restrict__ vb) {
    const int m0 = blockIdx.x * 128;
    const int n0 = blockIdx.y * 128;
    GEMM_MAINLOOP(A, Bt, m0, n0)
    const int col   = lane & 15;
    const int rbase = (lane >> 4) * 4;
    for (int nn = 0; nn < 4; ++nn) {
        int n = n0 + wc * 64 + nn * 16 + col;
        float bv = bias[n];
        int which = n >> 10;
        int c  = n & 1023;
        int h  = c >> 6;
        int dh = c & 63;
        bf16* dst = (which == 0) ? qb : ((which == 1) ? kb : vb);
        const float sc = (which == 0) ? CS_LOG2E : 1.0f;
        for (int mm = 0; mm < 4; ++mm) {
            for (int i = 0; i < 4; ++i) {
                int m = m0 + wr * 64 + mm * 16 + rbase + i;
                int b_ = m >> 11;
                int t  = m & 2047;
                dst[(((b_ * N_HEAD + h) * T_SEQ) + t) * HEAD_DIM + dh] =
                    f2b((acc[mm][nn][i] + bv) * sc);
            }
        }
    }
}

// ---------------- proj GEMM (64x128 tiles) ----------------
__global__ __launch_bounds__(256) void k_gemm_proj(const bf16* __restrict__ A,
                                                   const bf16* __restrict__ Bt,
                                                   const float* __restrict__ bias,
                                                   float* __restrict__ out) {
    const int m0 = blockIdx.x * 64;
    const int n0 = blockIdx.y * 128;
    GEMM_MAINLOOP_64(A, Bt, m0, n0)
    const int col   = lane & 15;
    const int rbase = (lane >> 4) * 4;
    for (int nn = 0; nn < 4; ++nn) {
        int n = n0 + wc * 64 + nn * 16 + col;
        float bv = bias[n];
        for (int mm = 0; mm < 2; ++mm) {
            for (int i = 0; i < 4; ++i) {
                int m = m0 + wr * 32 + mm * 16 + rbase + i;
                out[(size_t)m * N_EMB + n] = acc[mm][nn][i] + bv;
            }
        }
    }
}

// =====================================================================
// flash attention helpers (swapped-operand 32x32; Q pre-scaled so S is
// already in log2 units). Cross-lane via __shfl_xor (proven R4-R6).
// =====================================================================
__device__ __forceinline__ void pv_group(const float* p, int hi,
                                         const bf16x8 (&va)[2][2], f32x16 (&o)[2]) {
    u32 c[8], sw[8];
    #pragma unroll
    for (int i = 0; i < 8; ++i) c[i] = pkbf(p[2 * i], p[2 * i + 1]);
    #pragma unroll
    for (int i = 0; i < 8; ++i) sw[i] = __shfl_xor(c[i], 32, 64);
    u32x4 f0, f1;
    f0[0] = hi ? sw[2] : c[0];  f0[1] = hi ? sw[3] : c[1];
    f0[2] = hi ? c[2]  : sw[0]; f0[3] = hi ? c[3]  : sw[1];
    f1[0] = hi ? sw[6] : c[4];  f1[1] = hi ? sw[7] : c[5];
    f1[2] = hi ? c[6]  : sw[4]; f1[3] = hi ? c[7]  : sw[5];
    bf16x8 pb0 = __builtin_bit_cast(bf16x8, f0);
    bf16x8 pb1 = __builtin_bit_cast(bf16x8, f1);
    __builtin_amdgcn_s_setprio(1);
    #pragma unroll
    for (int dt = 0; dt < 2; ++dt) {
        o[dt] = __builtin_amdgcn_mfma_f32_32x32x16_bf16(va[dt][0], pb0, o[dt], 0, 0, 0);
        o[dt] = __builtin_amdgcn_mfma_f32_32x32x16_bf16(va[dt][1], pb1, o[dt], 0, 0, 0);
    }
    __builtin_amdgcn_s_setprio(0);
}

__device__ __forceinline__ void load_va(const bf16* __restrict__ Vt, int kbase,
                                        int qr, int hi, bf16x8 (&va)[2][2]) {
    #pragma unroll
    for (int dt = 0; dt < 2; ++dt)
        #pragma unroll
        for (int ks = 0; ks < 2; ++ks)
            va[dt][ks] = *reinterpret_cast<const bf16x8*>(
                Vt + (size_t)(dt * 32 + qr) * T_SEQ + kbase + ks * 16 + hi * 8);
}

__device__ __forceinline__ float tree_max16(const f32x16& v) {
    float a0 = fmaxf(v[0], v[1]),   a1 = fmaxf(v[2], v[3]);
    float a2 = fmaxf(v[4], v[5]),   a3 = fmaxf(v[6], v[7]);
    float a4 = fmaxf(v[8], v[9]),   a5 = fmaxf(v[10], v[11]);
    float a6 = fmaxf(v[12], v[13]), a7 = fmaxf(v[14], v[15]);
    float b0 = fmaxf(a0, a1), b1 = fmaxf(a2, a3);
    float b2 = fmaxf(a4, a5), b3 = fmaxf(a6, a7);
    return fmaxf(fmaxf(b0, b1), fmaxf(b2, b3));
}

// 64-wide KV tile; DIAG_HI: second 32-group is the diagonal (mask kpos<=qr)
// VGPR discipline: V-fragments loaded LATE (va0 before exp2, va1 after first
// pv_group) to keep peak live range under the 3-waves/SIMD cap.
template<bool DIAG_HI>
__device__ __forceinline__ void attn_tile64(
    const bf16* __restrict__ K, const bf16* __restrict__ Vt, int kbase,
    int qr, int hi, const bf16x8 (&qf)[4],
    float& m_r, float& l_r, f32x16 (&o)[2]) {
    bf16x8 kf0[4], kf1[4];
    #pragma unroll
    for (int f = 0; f < 4; ++f) {
        kf0[f] = *reinterpret_cast<const bf16x8*>(
            K + (size_t)(kbase + qr) * HEAD_DIM + f * 16 + hi * 8);
        kf1[f] = *reinterpret_cast<const bf16x8*>(
            K + (size_t)(kbase + 32 + qr) * HEAD_DIM + f * 16 + hi * 8);
    }
    f32x16 st0, st1;
    #pragma unroll
    for (int r = 0; r < 16; ++r) { st0[r] = 0.f; st1[r] = 0.f; }
    __builtin_amdgcn_s_setprio(1);
    #pragma unroll
    for (int f = 0; f < 4; ++f)
        st0 = __builtin_amdgcn_mfma_f32_32x32x16_bf16(kf0[f], qf[f], st0, 0, 0, 0);
    #pragma unroll
    for (int f = 0; f < 4; ++f)
        st1 = __builtin_amdgcn_mfma_f32_32x32x16_bf16(kf1[f], qf[f], st1, 0, 0, 0);
    __builtin_amdgcn_s_setprio(0);
    if (DIAG_HI) {
        const int kp4 = 4 * hi;
        #pragma unroll
        for (int r = 0; r < 16; ++r) {
            const int kpos = (r & 3) + 8 * (r >> 2) + kp4;
            if (kpos > qr) st1[r] = -3.0e38f;
        }
    }
    float mt = fmaxf(tree_max16(st0), tree_max16(st1));
    mt = xhalf_max(mt);
    if (!__all(mt <= m_r + 8.f)) {       // defer-max (T13), log2 domain
        const float mn = fmaxf(m_r, mt);
        const float alpha = exp2f(m_r - mn);
        m_r = mn;
        l_r *= alpha;
        #pragma unroll
        for (int r = 0; r < 16; ++r) { o[0][r] *= alpha; o[1][r] *= alpha; }
    }
    bf16x8 va0[2][2];
    load_va(Vt, kbase, qr, hi, va0);           // latency hides under exp2 below
    float p0[16], p1[16];
    #pragma unroll
    for (int r = 0; r < 16; ++r) { p0[r] = exp2f(st0[r] - m_r); }
    #pragma unroll
    for (int r = 0; r < 16; ++r) { p1[r] = exp2f(st1[r] - m_r); }
    float s0 = 0.f, s1 = 0.f;
    #pragma unroll
    for (int r = 0; r < 8; ++r) { s0 += p0[r] + p0[r + 8]; s1 += p1[r] + p1[r + 8]; }
    l_r += xhalf_sum(s0 + s1);
    pv_group(p0, hi, va0, o);
    bf16x8 va1[2][2];
    load_va(Vt, kbase + 32, qr, hi, va1);      // latency hides under pv_group(p0)
    pv_group(p1, hi, va1, o);
}

// 32-wide KV tile; DIAG_MASK: apply causal mask
template<bool DIAG_MASK>
__device__ __forceinline__ void attn_tile32(
    const bf16* __restrict__ K, const bf16* __restrict__ Vt, int kbase,
    int qr, int hi, const bf16x8 (&qf)[4],
    float& m_r, float& l_r, f32x16 (&o)[2]) {
    bf16x8 kf[4];
    #pragma unroll
    for (int f = 0; f < 4; ++f)
        kf[f] = *reinterpret_cast<const bf16x8*>(
            K + (size_t)(kbase + qr) * HEAD_DIM + f * 16 + hi * 8);
    f32x16 st;
    #pragma unroll
    for (int r = 0; r < 16; ++r) st[r] = 0.f;
    __builtin_amdgcn_s_setprio(1);
    #pragma unroll
    for (int f = 0; f < 4; ++f)
        st = __builtin_amdgcn_mfma_f32_32x32x16_bf16(kf[f], qf[f], st, 0, 0, 0);
    __builtin_amdgcn_s_setprio(0);
    if (DIAG_MASK) {
        const int kp4 = 4 * hi;
        #pragma unroll
        for (int r = 0; r < 16; ++r) {
            const int kpos = (r & 3) + 8 * (r >> 2) + kp4;
            if (kpos > qr) st[r] = -3.0e38f;
        }
    }
    float mt = xhalf_max(tree_max16(st));
    if (!__all(mt <= m_r + 8.f)) {
        const float mn = fmaxf(m_r, mt);
        const float alpha = exp2f(m_r - mn);
        m_r = mn;
        l_r *= alpha;
        #pragma unroll
        for (int r = 0; r < 16; ++r) { o[0][r] *= alpha; o[1][r] *= alpha; }
    }
    bf16x8 va[2][2];
    load_va(Vt, kbase, qr, hi, va);
    float p[16];
    #pragma unroll
    for (int r = 0; r < 16; ++r) p[r] = exp2f(st[r] - m_r);
    float s = 0.f;
    #pragma unroll
    for (int r = 0; r < 8; ++r) s += p[r] + p[r + 8];
    l_r += xhalf_sum(s);
    pv_group(p, hi, va, o);
}

// =====================================================================
// flash attention: block = 2 waves sharing (bh, qblk); split-K halves,
// flash-combine via LDS. grid (bh=32, j=64): lin id % 8 = bh % 8 -> head
// pinned to XCD; qblk = 63-j -> heavy blocks dispatch first.
// launch_bounds(128,3): VGPR cap ~170 (need ~140, NO SPILL — R8's
// (128,4) capped at 64 VGPR and spilled 230 MB to scratch).
// =====================================================================
__global__ __launch_bounds__(128, 3) void k_attn(const bf16* __restrict__ qb,
                                                 const bf16* __restrict__ kb,
                                                 const bf16* __restrict__ vtb,
                                                 bf16* __restrict__ yb) {
    const int lane = threadIdx.x & 63;
    const int wv   = threadIdx.x >> 6;   // 0 or 1
    const int bh   = blockIdx.x;         // 0..31  (XCD = bh % 8)
    const int qblk = 63 - blockIdx.y;
    const int q0   = qblk * 32;
    const int b    = bh >> 4;
    const int h    = bh & 15;

    const bf16* Q  = qb  + (size_t)bh * T_SEQ * HEAD_DIM;
    const bf16* K  = kb  + (size_t)bh * T_SEQ * HEAD_DIM;
    const bf16* Vt = vtb + (size_t)bh * HEAD_DIM * T_SEQ;

    const int qr = lane & 31;
    const int hi = lane >> 5;

    bf16x8 qf[4];
    #pragma unroll
    for (int f = 0; f < 4; ++f)
        qf[f] = *reinterpret_cast<const bf16x8*>(
            Q + (size_t)(q0 + qr) * HEAD_DIM + f * 16 + hi * 8);

    f32x16 o[2];
    #pragma unroll
    for (int r = 0; r < 16; ++r) { o[0][r] = 0.f; o[1][r] = 0.f; }
    float m_r = -3.0e38f, l_r = 0.f;

    // split-K: wave0 = tiles [0, h0), wave1 = [h0, n) (incl. diagonal)
    const int n  = qblk + 1;
    const int h0 = n - (n >> 1);
    const int lo  = wv ? h0 : 0;
    const int end = wv ? n  : h0;
    const bool has_diag = (end == n) && (end > lo);
    const int nd_end = has_diag ? end - 1 : end;

    int t = lo;
    while (t + 2 <= nd_end) {
        attn_tile64<false>(K, Vt, t * 32, qr, hi, qf, m_r, l_r, o);
        t += 2;
    }
    if (has_diag) {
        if (nd_end - t == 1)
            attn_tile64<true>(K, Vt, t * 32, qr, hi, qf, m_r, l_r, o);
        else
            attn_tile32<true>(K, Vt, qblk * 32, qr, hi, qf, m_r, l_r, o);
    } else if (t < end) {
        attn_tile32<false>(K, Vt, t * 32, qr, hi, qf, m_r, l_r, o);
    }

    // ---- flash-combine across the 2 waves via LDS ----
    __shared__ float ls_o[64][33];   // +1 pad: conflict-free column reads
    __shared__ float ls_m[64];
    __shared__ float ls_l[64];
    if (wv == 1) {
        #pragma unroll
        for (int i = 0; i < 16; ++i) {
            ls_o[lane][i]      = o[0][i];
            ls_o[lane][16 + i] = o[1][i];
        }
        ls_m[lane] = m_r;
        ls_l[lane] = l_r;
    }
    __syncthreads();
    if (wv == 1) return;
    const float m1 = ls_m[lane];
    const float l1 = ls_l[lane];
    const float mN = fmaxf(m_r, m1);
    const float a0 = exp2f(m_r - mN);
    const float a1 = (m1 > -1.0e37f) ? exp2f(m1 - mN) : 0.f;  // guard empty wave1
    l_r = l_r * a0 + l1 * a1;
    #pragma unroll
    for (int i = 0; i < 16; ++i) {
        o[0][i] = o[0][i] * a0 + ls_o[lane][i]      * a1;
        o[1][i] = o[1][i] * a0 + ls_o[lane][16 + i] * a1;
    }

    // epilogue: O^T[d][q] / l  -> y[b][t][h*64+d]
    const float inv = 1.f / fmaxf(l_r, 1e-30f);
    const int tq = q0 + qr;
    bf16* yrow = yb + ((size_t)(b * T_SEQ + tq)) * N_EMB + h * HEAD_DIM;
    #pragma unroll
    for (int dt = 0; dt < 2; ++dt) {
        #pragma unroll
        for (int rr = 0; rr < 4; ++rr) {
            const int d0 = dt * 32 + 8 * rr + 4 * hi;
            ushort4 u;
            u.x = f2bu(o[dt][4 * rr + 0] * inv);
            u.y = f2bu(o[dt][4 * rr + 1] * inv);
            u.z = f2bu(o[dt][4 * rr + 2] * inv);
            u.w = f2bu(o[dt][4 * rr + 3] * inv);
            *reinterpret_cast<ushort4*>(yrow + d0) = u;
        }
    }
}

extern "C" void kernel_launch(void* const* d_in, const int* in_sizes, int n_in,
                              void* d_out, int out_size, void* d_ws, size_t ws_size,
                              hipStream_t stream) {
    const float* x      = (const float*)d_in[0];
    const float* W_attn = (const float*)d_in[1];
    const float* b_attn = (const float*)d_in[2];
    const float* W_proj = (const float*)d_in[3];
    const float* b_proj = (const float*)d_in[4];
    float* out = (float*)d_out;

    const size_t sz_x   = (size_t)M_TOT * N_EMB;
    const size_t sz_wat = (size_t)N_QKV * N_EMB;
    const size_t sz_wpt = (size_t)N_EMB * N_EMB;
    const size_t sz_hd  = (size_t)BATCH * N_HEAD * T_SEQ * HEAD_DIM;
    const size_t need = (sz_x + sz_wat + sz_wpt + 3 * sz_hd + sz_x) * sizeof(bf16);
    if (ws_size < need) return;

    bf16* xb  = (bf16*)d_ws;       // dead after QKV GEMM -> reused for V^T
    bf16* wat = xb + sz_x;
    bf16* wpt = wat + sz_wat;
    bf16* qb  = wpt + sz_wpt;
    bf16* kbf = qb + sz_hd;
    bf16* vbf = kbf + sz_hd;
    bf16* yb  = vbf + sz_hd;
    bf16* vtb = xb;                // V^T [B,H,64,T]

    k_cast<<<dim3((sz_x / 4 + 255) / 256), 256, 0, stream>>>(x, xb, (int)(sz_x / 4));
    k_transpose<<<dim3(N_EMB / 32, N_QKV / 32), 256, 0, stream>>>(W_attn, wat, N_EMB, N_QKV);
    k_transpose<<<dim3(N_EMB / 32, N_EMB / 32), 256, 0, stream>>>(W_proj, wpt, N_EMB, N_EMB);
    k_gemm_qkv<<<dim3(M_TOT / 128, N_QKV / 128), 256, 0, stream>>>(xb, wat, b_attn, qb, kbf, vbf);
    k_vtrans<<<dim3(T_SEQ / 64, BATCH * N_HEAD), 256, 0, stream>>>(vbf, vtb);
    k_attn<<<dim3(BATCH * N_HEAD, 64), 128, 0, stream>>>(qb, kbf, vtb, yb);
    k_gemm_proj<<<dim3(M_TOT / 64, N_EMB / 128), 256, 0, stream>>>(yb, wpt, b_proj, out);
}